// Round 1
// baseline (438.536 us; speedup 1.0000x reference)
//
#include <hip/hip_runtime.h>
#include <math.h>

#define N_NODES 60000
#define M1_N    40000
#define M2_N    40000
#define DD      64
#define S0_N    10
#define S1_N    20
#define R_TOTAL (N_NODES + M1_N + M2_N)

__device__ __forceinline__ float wave_sum(float x) {
#pragma unroll
    for (int o = 32; o >= 1; o >>= 1) x += __shfl_xor(x, o, 64);
    return x;
}
__device__ __forceinline__ float wave_max(float x) {
#pragma unroll
    for (int o = 32; o >= 1; o >>= 1) x = fmaxf(x, __shfl_xor(x, o, 64));
    return x;
}

// Kernel 1: per-row projections + global-softmax reduction over all 140000 rows.
// One wave per row (lane = dim). Grid-stride; block-level partials -> 1 atomic set/block.
__global__ __launch_bounds__(256) void k_proj(
    const float* __restrict__ h0, const float* __restrict__ h1, const float* __restrict__ h2,
    const float* __restrict__ aw0, const float* __restrict__ aw1, const float* __restrict__ gatt,
    float* __restrict__ accum,
    float* __restrict__ p0r0, float* __restrict__ p0r1,
    float* __restrict__ p1, float* __restrict__ p2)
{
    __shared__ float s_wsum[64];
    __shared__ float s_se;
    const int tid = threadIdx.x, lane = tid & 63, wid = tid >> 6;
    if (tid < 64) s_wsum[tid] = 0.f;
    if (tid == 0) s_se = 0.f;
    __syncthreads();

    const float g   = gatt[lane];
    const float a0r = aw0[lane],      a1r = aw1[lane];
    const float a0n = aw0[64 + lane], a1n = aw1[64 + lane];

    float r_wsum = 0.f, r_se = 0.f;
    const int gw = blockIdx.x * 4 + wid;
    const int nw = gridDim.x * 4;
    for (int r = gw; r < R_TOTAL; r += nw) {
        float v;
        if (r < N_NODES)             v = h0[r * DD + lane];
        else if (r < N_NODES + M1_N) v = h1[(r - N_NODES) * DD + lane];
        else                         v = h2[(r - N_NODES - M1_N) * DD + lane];

        // global attention score: dot(row, glob_att)/sqrt(64)
        const float s  = wave_sum(v * g) * 0.125f;
        const float es = __expf(s);     // |s| < ~1, no max-subtraction needed
        r_se   += es;
        r_wsum += es * v;

        if (r < N_NODES) {
            const float q0 = wave_sum(v * a0r);
            const float q1 = wave_sum(v * a1r);
            if (lane == 0) { p0r0[r] = q0; p0r1[r] = q1; }
        } else if (r < N_NODES + M1_N) {
            const float q = wave_sum(v * a0n);
            if (lane == 0) p1[r - N_NODES] = q;
        } else {
            const float q = wave_sum(v * a1n);
            if (lane == 0) p2[r - N_NODES - M1_N] = q;
        }
    }
    atomicAdd(&s_wsum[lane], r_wsum);
    if (lane == 0) atomicAdd(&s_se, r_se);
    __syncthreads();
    if (tid < 64) atomicAdd(&accum[4 + tid], s_wsum[tid]);
    if (tid == 0) atomicAdd(&accum[2], s_se);
}

// Kernel 2: per-node neighbor attention (one wave per node, lane = dim),
// ELU, e0/e1 store, fused beta (tanh-GEMV + fus dot) reduction.
__global__ __launch_bounds__(256) void k_attn(
    const float* __restrict__ h1, const float* __restrict__ h2,
    const int* __restrict__ nei0, const int* __restrict__ nei1,
    const float* __restrict__ p0r0, const float* __restrict__ p0r1,
    const float* __restrict__ p1, const float* __restrict__ p2,
    const float* __restrict__ fcw, const float* __restrict__ fcb,
    const float* __restrict__ fus, float* __restrict__ accum,
    float* __restrict__ e0, float* __restrict__ e1)
{
    __shared__ float s_fcw[64 * 65];   // +1 pad: bank = (row+col)%32, 2-way = free
    __shared__ float s_b0, s_b1;
    const int tid = threadIdx.x, lane = tid & 63, wid = tid >> 6;
#pragma unroll
    for (int i = 0; i < 16; i++) {
        const int idx = i * 256 + tid;
        s_fcw[(idx >> 6) * 65 + (idx & 63)] = fcw[idx];
    }
    if (tid == 0) { s_b0 = 0.f; s_b1 = 0.f; }
    __syncthreads();

    const float fb = fcb[lane];
    const float fu = fus[lane];
    const float* fcrow = &s_fcw[lane * 65];

    float rb0 = 0.f, rb1 = 0.f;
    const int gw = blockIdx.x * 4 + wid;
    const int nw = gridDim.x * 4;
    for (int n = gw; n < N_NODES; n += nw) {
        // ---- e0: S0=10 neighbors from h1 ----
        {
            float sc = -INFINITY; int idx = 0;
            if (lane < S0_N) {
                idx = nei0[n * S0_N + lane];
                const float t = p0r0[n] + p1[idx];
                sc = (t >= 0.f) ? t : 0.01f * t;       // leaky_relu(0.01)
            }
            const float m   = wave_max(sc);
            const float w   = __expf(sc - m);           // 0 for lanes >= S0
            const float inv = 1.f / wave_sum(w);
            float e = 0.f;
#pragma unroll
            for (int s = 0; s < S0_N; s++) {
                const float ws = __shfl(w, s, 64) * inv;
                const int   id = __shfl(idx, s, 64);
                e = fmaf(ws, h1[id * DD + lane], e);
            }
            e = (e > 0.f) ? e : (__expf(e) - 1.f);      // ELU
            e0[n * DD + lane] = e;
            float acc = fb;
#pragma unroll
            for (int k = 0; k < 64; k++) acc = fmaf(__shfl(e, k, 64), fcrow[k], acc);
            rb0 += wave_sum(tanhf(acc) * fu);
        }
        // ---- e1: S1=20 neighbors from h2 ----
        {
            float sc = -INFINITY; int idx = 0;
            if (lane < S1_N) {
                idx = nei1[n * S1_N + lane];
                const float t = p0r1[n] + p2[idx];
                sc = (t >= 0.f) ? t : 0.01f * t;
            }
            const float m   = wave_max(sc);
            const float w   = __expf(sc - m);
            const float inv = 1.f / wave_sum(w);
            float e = 0.f;
#pragma unroll
            for (int s = 0; s < S1_N; s++) {
                const float ws = __shfl(w, s, 64) * inv;
                const int   id = __shfl(idx, s, 64);
                e = fmaf(ws, h2[id * DD + lane], e);
            }
            e = (e > 0.f) ? e : (__expf(e) - 1.f);
            e1[n * DD + lane] = e;
            float acc = fb;
#pragma unroll
            for (int k = 0; k < 64; k++) acc = fmaf(__shfl(e, k, 64), fcrow[k], acc);
            rb1 += wave_sum(tanhf(acc) * fu);
        }
    }
    if (lane == 0) { atomicAdd(&s_b0, rb0); atomicAdd(&s_b1, rb1); }
    __syncthreads();
    if (tid == 0) { atomicAdd(&accum[0], s_b0); atomicAdd(&accum[1], s_b1); }
}

// Kernel 3: final elementwise combine. Scalars (beta softmax, sigmoid gate,
// global embed normalize) recomputed per thread from cached accum reads.
__global__ __launch_bounds__(256) void k_out(
    const float* __restrict__ e0, const float* __restrict__ e1,
    const float* __restrict__ accum, const float* __restrict__ gate,
    float* __restrict__ out)
{
    const int i = blockIdx.x * 256 + threadIdx.x;   // float4 index, exact grid
    const float b0 = accum[0] * (1.f / N_NODES);
    const float b1 = accum[1] * (1.f / N_NODES);
    const float m  = fmaxf(b0, b1);
    const float eb0 = __expf(b0 - m), eb1 = __expf(b1 - m);
    const float gv  = 1.f / (1.f + __expf(-gate[0]));
    const float c0  = gv * eb0 / (eb0 + eb1);
    const float c1  = gv * eb1 / (eb0 + eb1);
    const float cg  = (1.f - gv) / accum[2];

    const float4 av = ((const float4*)(accum + 4))[i & 15];
    const float4 a  = ((const float4*)e0)[i];
    const float4 b  = ((const float4*)e1)[i];
    float4 o;
    o.x = c0 * a.x + c1 * b.x + cg * av.x;
    o.y = c0 * a.y + c1 * b.y + cg * av.y;
    o.z = c0 * a.z + c1 * b.z + cg * av.z;
    o.w = c0 * a.w + c1 * b.w + cg * av.w;
    ((float4*)out)[i] = o;
}

extern "C" void kernel_launch(void* const* d_in, const int* in_sizes, int n_in,
                              void* d_out, int out_size, void* d_ws, size_t ws_size,
                              hipStream_t stream) {
    (void)in_sizes; (void)n_in; (void)out_size; (void)ws_size;
    const float* h0   = (const float*)d_in[0];
    const float* h1   = (const float*)d_in[1];
    const float* h2   = (const float*)d_in[2];
    const int*   nei0 = (const int*)  d_in[3];
    const int*   nei1 = (const int*)  d_in[4];
    const float* aw0  = (const float*)d_in[5];
    const float* aw1  = (const float*)d_in[6];
    const float* fcw  = (const float*)d_in[7];
    const float* fcb  = (const float*)d_in[8];
    const float* fus  = (const float*)d_in[9];
    const float* gatt = (const float*)d_in[10];
    const float* gate = (const float*)d_in[11];
    float* out = (float*)d_out;

    // workspace layout (floats)
    float* ws    = (float*)d_ws;
    float* accum = ws;                       // [0]=b0 [1]=b1 [2]=sumexp [4..67]=wsum
    float* p0r0  = ws + 256;                 // N
    float* p0r1  = p0r0 + N_NODES;           // N
    float* p1    = p0r1 + N_NODES;           // M1
    float* p2    = p1 + M1_N;                // M2
    float* e0    = p2 + M2_N;                // N*64 (16B-aligned: offset 200256)
    float* e1    = e0 + (size_t)N_NODES * DD;

    hipMemsetAsync(accum, 0, 256 * sizeof(float), stream);
    k_proj<<<1024, 256, 0, stream>>>(h0, h1, h2, aw0, aw1, gatt, accum, p0r0, p0r1, p1, p2);
    k_attn<<<2048, 256, 0, stream>>>(h1, h2, nei0, nei1, p0r0, p0r1, p1, p2,
                                     fcw, fcb, fus, accum, e0, e1);
    k_out<<<(N_NODES * DD / 4) / 256, 256, 0, stream>>>(e0, e1, accum, gate, out);
}

// Round 2
// 293.740 us; speedup vs baseline: 1.4929x; 1.4929x over previous
//
#include <hip/hip_runtime.h>
#include <math.h>

#define N_NODES 60000
#define M1_N    40000
#define M2_N    40000
#define DD      64
#define S0_N    10
#define S1_N    20
#define R_TOTAL (N_NODES + M1_N + M2_N)

__device__ __forceinline__ float wave_sum(float x) {
#pragma unroll
    for (int o = 32; o >= 1; o >>= 1) x += __shfl_xor(x, o, 64);
    return x;
}
__device__ __forceinline__ float bcast(float v, int l) {
    return __uint_as_float(__builtin_amdgcn_readlane(__float_as_uint(v), l));
}
__device__ __forceinline__ float tanh_fast(float x) {
    return 1.f - 2.f / (__expf(2.f * x) + 1.f);
}

// Kernel 1: per-row projections + global-softmax reduction over all 140000 rows.
__global__ __launch_bounds__(256) void k_proj(
    const float* __restrict__ h0, const float* __restrict__ h1, const float* __restrict__ h2,
    const float* __restrict__ aw0, const float* __restrict__ aw1, const float* __restrict__ gatt,
    float* __restrict__ accum,
    float* __restrict__ p0r0, float* __restrict__ p0r1,
    float* __restrict__ p1, float* __restrict__ p2)
{
    __shared__ float s_wsum[64];
    __shared__ float s_se;
    const int tid = threadIdx.x, lane = tid & 63, wid = tid >> 6;
    if (tid < 64) s_wsum[tid] = 0.f;
    if (tid == 0) s_se = 0.f;
    __syncthreads();

    const float g   = gatt[lane];
    const float a0r = aw0[lane],      a1r = aw1[lane];
    const float a0n = aw0[64 + lane], a1n = aw1[64 + lane];

    float r_wsum = 0.f, r_se = 0.f;
    const int gw = blockIdx.x * 4 + wid;
    const int nw = gridDim.x * 4;
    for (int r = gw; r < R_TOTAL; r += nw) {
        float v;
        if (r < N_NODES)             v = h0[r * DD + lane];
        else if (r < N_NODES + M1_N) v = h1[(r - N_NODES) * DD + lane];
        else                         v = h2[(r - N_NODES - M1_N) * DD + lane];

        const float s  = wave_sum(v * g) * 0.125f;
        const float es = __expf(s);     // |s| small; no max-subtraction needed
        r_se   += es;
        r_wsum += es * v;

        if (r < N_NODES) {
            const float q0 = wave_sum(v * a0r);
            const float q1 = wave_sum(v * a1r);
            if (lane == 0) { p0r0[r] = q0; p0r1[r] = q1; }
        } else if (r < N_NODES + M1_N) {
            const float q = wave_sum(v * a0n);
            if (lane == 0) p1[r - N_NODES] = q;
        } else {
            const float q = wave_sum(v * a1n);
            if (lane == 0) p2[r - N_NODES - M1_N] = q;
        }
    }
    atomicAdd(&s_wsum[lane], r_wsum);
    if (lane == 0) atomicAdd(&s_se, r_se);
    __syncthreads();
    if (tid < 64) atomicAdd(&accum[4 + tid], s_wsum[tid]);
    if (tid == 0) atomicAdd(&accum[2], s_se);
}

// Kernel 2: per-node neighbor attention (one wave per node, lane = dim),
// ELU, e0/e1 store. No beta work here (moved to k_beta) -> no LDS, few shuffles.
__global__ __launch_bounds__(256) void k_attn(
    const float* __restrict__ h1, const float* __restrict__ h2,
    const int* __restrict__ nei0, const int* __restrict__ nei1,
    const float* __restrict__ p0r0, const float* __restrict__ p0r1,
    const float* __restrict__ p1, const float* __restrict__ p2,
    float* __restrict__ e0, float* __restrict__ e1)
{
    const int tid = threadIdx.x, lane = tid & 63, wid = tid >> 6;
    const int gw = blockIdx.x * 4 + wid;
    const int nw = gridDim.x * 4;
    for (int n = gw; n < N_NODES; n += nw) {
        const float pr0 = p0r0[n];
        const float pr1 = p0r1[n];
        // ---- e0: S0=10 neighbors from h1 ----
        {
            float w = 0.f; int idx = 0;
            if (lane < S0_N) {
                idx = nei0[n * S0_N + lane];
                float t = pr0 + p1[idx];
                t = (t >= 0.f) ? t : 0.01f * t;     // leaky_relu(0.01)
                w = __expf(t);                       // scores bounded (~N(0,1.5)); no max-sub
            }
            const float inv = 1.f / wave_sum(w);
            float ea = 0.f, eb = 0.f;
#pragma unroll
            for (int s = 0; s < S0_N; s += 2) {
                const float w0 = bcast(w, s);
                const int   i0 = __builtin_amdgcn_readlane(idx, s);
                const float w1 = bcast(w, s + 1);
                const int   i1 = __builtin_amdgcn_readlane(idx, s + 1);
                ea = fmaf(w0, h1[i0 * DD + lane], ea);
                eb = fmaf(w1, h1[i1 * DD + lane], eb);
            }
            float e = (ea + eb) * inv;
            e = (e > 0.f) ? e : (__expf(e) - 1.f);   // ELU
            e0[n * DD + lane] = e;
        }
        // ---- e1: S1=20 neighbors from h2 ----
        {
            float w = 0.f; int idx = 0;
            if (lane < S1_N) {
                idx = nei1[n * S1_N + lane];
                float t = pr1 + p2[idx];
                t = (t >= 0.f) ? t : 0.01f * t;
                w = __expf(t);
            }
            const float inv = 1.f / wave_sum(w);
            float ea = 0.f, eb = 0.f;
#pragma unroll
            for (int s = 0; s < S1_N; s += 2) {
                const float w0 = bcast(w, s);
                const int   i0 = __builtin_amdgcn_readlane(idx, s);
                const float w1 = bcast(w, s + 1);
                const int   i1 = __builtin_amdgcn_readlane(idx, s + 1);
                ea = fmaf(w0, h2[i0 * DD + lane], ea);
                eb = fmaf(w1, h2[i1 * DD + lane], eb);
            }
            float e = (ea + eb) * inv;
            e = (e > 0.f) ? e : (__expf(e) - 1.f);
            e1[n * DD + lane] = e;
        }
    }
}

// Kernel 3: beta reduction. One wave per node, lane = output dim j.
// fc_w row j held in registers (16 x float4); e-row broadcast via readlane.
// Per-lane partial accumulated across nodes; single wave reduce at the end.
__global__ __launch_bounds__(256) void k_beta(
    const float* __restrict__ e0, const float* __restrict__ e1,
    const float* __restrict__ fcw, const float* __restrict__ fcb,
    const float* __restrict__ fus, float* __restrict__ accum)
{
    __shared__ float s_part[2];
    const int tid = threadIdx.x, lane = tid & 63, wid = tid >> 6;
    if (tid < 2) s_part[tid] = 0.f;
    float4 fw[16];
#pragma unroll
    for (int k = 0; k < 16; k++) fw[k] = ((const float4*)(fcw + lane * DD))[k];
    const float fb = fcb[lane], fu = fus[lane];
    __syncthreads();

    float rb0 = 0.f, rb1 = 0.f;
    const int gw = blockIdx.x * 4 + wid;
    const int nw = gridDim.x * 4;
    for (int n = gw; n < N_NODES; n += nw) {
        {
            const float ev = e0[n * DD + lane];
            float a0 = 0.f, a1 = 0.f, a2 = 0.f, a3 = 0.f;
#pragma unroll
            for (int k = 0; k < 16; k++) {
                a0 = fmaf(bcast(ev, 4 * k + 0), fw[k].x, a0);
                a1 = fmaf(bcast(ev, 4 * k + 1), fw[k].y, a1);
                a2 = fmaf(bcast(ev, 4 * k + 2), fw[k].z, a2);
                a3 = fmaf(bcast(ev, 4 * k + 3), fw[k].w, a3);
            }
            rb0 += tanh_fast(((a0 + a1) + (a2 + a3)) + fb) * fu;
        }
        {
            const float ev = e1[n * DD + lane];
            float a0 = 0.f, a1 = 0.f, a2 = 0.f, a3 = 0.f;
#pragma unroll
            for (int k = 0; k < 16; k++) {
                a0 = fmaf(bcast(ev, 4 * k + 0), fw[k].x, a0);
                a1 = fmaf(bcast(ev, 4 * k + 1), fw[k].y, a1);
                a2 = fmaf(bcast(ev, 4 * k + 2), fw[k].z, a2);
                a3 = fmaf(bcast(ev, 4 * k + 3), fw[k].w, a3);
            }
            rb1 += tanh_fast(((a0 + a1) + (a2 + a3)) + fb) * fu;
        }
    }
    const float b0 = wave_sum(rb0);
    const float b1 = wave_sum(rb1);
    if (lane == 0) { atomicAdd(&s_part[0], b0); atomicAdd(&s_part[1], b1); }
    __syncthreads();
    if (tid == 0) { atomicAdd(&accum[0], s_part[0]); atomicAdd(&accum[1], s_part[1]); }
}

// Kernel 4: final elementwise combine.
__global__ __launch_bounds__(256) void k_out(
    const float* __restrict__ e0, const float* __restrict__ e1,
    const float* __restrict__ accum, const float* __restrict__ gate,
    float* __restrict__ out)
{
    const int i = blockIdx.x * 256 + threadIdx.x;   // float4 index, exact grid
    const float b0 = accum[0] * (1.f / N_NODES);
    const float b1 = accum[1] * (1.f / N_NODES);
    const float m  = fmaxf(b0, b1);
    const float eb0 = __expf(b0 - m), eb1 = __expf(b1 - m);
    const float gv  = 1.f / (1.f + __expf(-gate[0]));
    const float c0  = gv * eb0 / (eb0 + eb1);
    const float c1  = gv * eb1 / (eb0 + eb1);
    const float cg  = (1.f - gv) / accum[2];

    const float4 av = ((const float4*)(accum + 4))[i & 15];
    const float4 a  = ((const float4*)e0)[i];
    const float4 b  = ((const float4*)e1)[i];
    float4 o;
    o.x = c0 * a.x + c1 * b.x + cg * av.x;
    o.y = c0 * a.y + c1 * b.y + cg * av.y;
    o.z = c0 * a.z + c1 * b.z + cg * av.z;
    o.w = c0 * a.w + c1 * b.w + cg * av.w;
    ((float4*)out)[i] = o;
}

extern "C" void kernel_launch(void* const* d_in, const int* in_sizes, int n_in,
                              void* d_out, int out_size, void* d_ws, size_t ws_size,
                              hipStream_t stream) {
    (void)in_sizes; (void)n_in; (void)out_size; (void)ws_size;
    const float* h0   = (const float*)d_in[0];
    const float* h1   = (const float*)d_in[1];
    const float* h2   = (const float*)d_in[2];
    const int*   nei0 = (const int*)  d_in[3];
    const int*   nei1 = (const int*)  d_in[4];
    const float* aw0  = (const float*)d_in[5];
    const float* aw1  = (const float*)d_in[6];
    const float* fcw  = (const float*)d_in[7];
    const float* fcb  = (const float*)d_in[8];
    const float* fus  = (const float*)d_in[9];
    const float* gatt = (const float*)d_in[10];
    const float* gate = (const float*)d_in[11];
    float* out = (float*)d_out;

    float* ws    = (float*)d_ws;
    float* accum = ws;                       // [0]=b0 [1]=b1 [2]=sumexp [4..67]=wsum
    float* p0r0  = ws + 256;                 // N
    float* p0r1  = p0r0 + N_NODES;           // N
    float* p1    = p0r1 + N_NODES;           // M1
    float* p2    = p1 + M1_N;                // M2
    float* e0    = p2 + M2_N;                // N*64
    float* e1    = e0 + (size_t)N_NODES * DD;

    hipMemsetAsync(accum, 0, 256 * sizeof(float), stream);
    k_proj<<<1024, 256, 0, stream>>>(h0, h1, h2, aw0, aw1, gatt, accum, p0r0, p0r1, p1, p2);
    k_attn<<<2048, 256, 0, stream>>>(h1, h2, nei0, nei1, p0r0, p0r1, p1, p2, e0, e1);
    k_beta<<<2048, 256, 0, stream>>>(e0, e1, fcw, fcb, fus, accum);
    k_out<<<(N_NODES * DD / 4) / 256, 256, 0, stream>>>(e0, e1, accum, gate, out);
}

// Round 3
// 225.102 us; speedup vs baseline: 1.9482x; 1.3049x over previous
//
#include <hip/hip_runtime.h>
#include <math.h>

#define N_NODES 60000
#define M1_N    40000
#define M2_N    40000
#define DD      64
#define S0_N    10
#define S1_N    20
#define R_TOTAL (N_NODES + M1_N + M2_N)

typedef __attribute__((ext_vector_type(8))) short short8;   // 8 bf16 = 4 VGPRs
typedef __attribute__((ext_vector_type(4))) float f32x4;

__device__ __forceinline__ float wave_sum(float x) {
#pragma unroll
    for (int o = 32; o >= 1; o >>= 1) x += __shfl_xor(x, o, 64);
    return x;
}
__device__ __forceinline__ float bcast(float v, int l) {
    return __uint_as_float(__builtin_amdgcn_readlane(__float_as_uint(v), l));
}
__device__ __forceinline__ float tanh_fast(float x) {
    return 1.f - 2.f / (__expf(2.f * x) + 1.f);
}
// f32 -> bf16 with round-to-nearest-even
__device__ __forceinline__ unsigned short f2bf(float x) {
    unsigned u = __float_as_uint(x);
    return (unsigned short)((u + 0x7FFFu + ((u >> 16) & 1u)) >> 16);
}
__device__ __forceinline__ float bf2f(unsigned short u) {
    return __uint_as_float(((unsigned)u) << 16);
}

// Kernel 1: per-row projections + global-softmax reduction over all 140000 rows.
// Also emits bf16 copies of h1/h2 (halves k_attn's gather traffic).
__global__ __launch_bounds__(256) void k_proj(
    const float* __restrict__ h0, const float* __restrict__ h1, const float* __restrict__ h2,
    const float* __restrict__ aw0, const float* __restrict__ aw1, const float* __restrict__ gatt,
    float* __restrict__ accum,
    float* __restrict__ p0r0, float* __restrict__ p0r1,
    float* __restrict__ p1, float* __restrict__ p2,
    unsigned short* __restrict__ h1bf, unsigned short* __restrict__ h2bf)
{
    __shared__ float s_wsum[64];
    __shared__ float s_se;
    const int tid = threadIdx.x, lane = tid & 63, wid = tid >> 6;
    if (tid < 64) s_wsum[tid] = 0.f;
    if (tid == 0) s_se = 0.f;
    __syncthreads();

    const float g   = gatt[lane];
    const float a0r = aw0[lane],      a1r = aw1[lane];
    const float a0n = aw0[64 + lane], a1n = aw1[64 + lane];

    float r_wsum = 0.f, r_se = 0.f;
    const int gw = blockIdx.x * 4 + wid;
    const int nw = gridDim.x * 4;
    for (int r = gw; r < R_TOTAL; r += nw) {
        float v;
        if (r < N_NODES)             v = h0[r * DD + lane];
        else if (r < N_NODES + M1_N) v = h1[(r - N_NODES) * DD + lane];
        else                         v = h2[(r - N_NODES - M1_N) * DD + lane];

        const float s  = wave_sum(v * g) * 0.125f;
        const float es = __expf(s);     // |s| small; no max-subtraction needed
        r_se   += es;
        r_wsum += es * v;

        if (r < N_NODES) {
            const float q0 = wave_sum(v * a0r);
            const float q1 = wave_sum(v * a1r);
            if (lane == 0) { p0r0[r] = q0; p0r1[r] = q1; }
        } else if (r < N_NODES + M1_N) {
            const int rr = r - N_NODES;
            const float q = wave_sum(v * a0n);
            h1bf[rr * DD + lane] = f2bf(v);
            if (lane == 0) p1[rr] = q;
        } else {
            const int rr = r - N_NODES - M1_N;
            const float q = wave_sum(v * a1n);
            h2bf[rr * DD + lane] = f2bf(v);
            if (lane == 0) p2[rr] = q;
        }
    }
    atomicAdd(&s_wsum[lane], r_wsum);
    if (lane == 0) atomicAdd(&s_se, r_se);
    __syncthreads();
    if (tid < 64) atomicAdd(&accum[4 + tid], s_wsum[tid]);
    if (tid == 0) atomicAdd(&accum[2], s_se);
}

// Kernel 2: per-node neighbor attention. One wave per node, lane = dim.
// Both softmaxes share one 5-step half-wave butterfly (w0 lanes 0..9, w1 lanes 32..51).
// All 30 bf16 row-gathers issued before reduction. e0/e1 stored bf16.
__global__ __launch_bounds__(256) void k_attn(
    const unsigned short* __restrict__ h1bf, const unsigned short* __restrict__ h2bf,
    const int* __restrict__ nei0, const int* __restrict__ nei1,
    const float* __restrict__ p0r0, const float* __restrict__ p0r1,
    const float* __restrict__ p1, const float* __restrict__ p2,
    unsigned short* __restrict__ e0bf, unsigned short* __restrict__ e1bf)
{
    const int tid = threadIdx.x, lane = tid & 63, wid = tid >> 6;
    const bool grp0 = (lane < S0_N);
    const bool grp1 = (lane >= 32) && (lane < 32 + S1_N);
    const int gw = blockIdx.x * 4 + wid;
    const int nw = gridDim.x * 4;
    for (int n = gw; n < N_NODES; n += nw) {
        const float pr0 = p0r0[n];
        const float pr1 = p0r1[n];

        int idx = 0; float w = 0.f;
        if (grp0) idx = nei0[n * S0_N + lane];
        if (grp1) idx = nei1[n * S1_N + (lane - 32)];
        if (grp0 | grp1) {
            float t = (grp0 ? pr0 : pr1) + (grp0 ? p1[idx] : p2[idx]);
            t = (t >= 0.f) ? t : 0.01f * t;      // leaky_relu(0.01)
            w = __expf(t);                        // scores bounded; no max-sub
        }
        float sv = w;
#pragma unroll
        for (int o = 16; o >= 1; o >>= 1) sv += __shfl_xor(sv, o, 64);
        const float inv0 = 1.f / bcast(sv, 0);
        const float inv1 = 1.f / bcast(sv, 32);

        // issue all 30 gathers (independent -> in flight together)
        float v0[S0_N], v1[S1_N];
#pragma unroll
        for (int s = 0; s < S0_N; s++) {
            const int i0 = __builtin_amdgcn_readlane(idx, s);
            v0[s] = bf2f(h1bf[i0 * DD + lane]);
        }
#pragma unroll
        for (int s = 0; s < S1_N; s++) {
            const int i1 = __builtin_amdgcn_readlane(idx, 32 + s);
            v1[s] = bf2f(h2bf[i1 * DD + lane]);
        }

        {
            float ea = 0.f, eb = 0.f;
#pragma unroll
            for (int s = 0; s < S0_N; s += 2) {
                ea = fmaf(bcast(w, s),     v0[s],     ea);
                eb = fmaf(bcast(w, s + 1), v0[s + 1], eb);
            }
            float e = (ea + eb) * inv0;
            e = (e > 0.f) ? e : (__expf(e) - 1.f);   // ELU
            e0bf[n * DD + lane] = f2bf(e);
        }
        {
            float ea = 0.f, eb = 0.f, ec = 0.f, ed = 0.f;
#pragma unroll
            for (int s = 0; s < S1_N; s += 4) {
                ea = fmaf(bcast(w, 32 + s),     v1[s],     ea);
                eb = fmaf(bcast(w, 33 + s),     v1[s + 1], eb);
                ec = fmaf(bcast(w, 34 + s),     v1[s + 2], ec);
                ed = fmaf(bcast(w, 35 + s),     v1[s + 3], ed);
            }
            float e = ((ea + eb) + (ec + ed)) * inv1;
            e = (e > 0.f) ? e : (__expf(e) - 1.f);
            e1bf[n * DD + lane] = f2bf(e);
        }
    }
}

// Kernel 3: beta reduction via MFMA. Per 16-node tile: T = E_tile @ fcw^T via
// 16x16x32_bf16 (4 col-tiles x 2 K-halves), then tanh, dot with fus, reduce.
// fcw^T fragments live in 32 VGPRs and are used by every MFMA (can't be sunk).
__global__ __launch_bounds__(256) void k_beta(
    const unsigned short* __restrict__ e0bf, const unsigned short* __restrict__ e1bf,
    const float* __restrict__ fcw, const float* __restrict__ fcb,
    const float* __restrict__ fus, float* __restrict__ accum)
{
    __shared__ float s_part[2];
    const int tid = threadIdx.x, lane = tid & 63, wid = tid >> 6;
    if (tid < 2) s_part[tid] = 0.f;
    const int m = lane & 15, q = lane >> 4;

    short8 bfr[4][2];          // B-frag: lane holds fcw[n=t*16+m][k = h*32 + q*8 + j]
    float fb[4], fu[4];
#pragma unroll
    for (int t = 0; t < 4; t++) {
        const float* wrow = fcw + (t * 16 + m) * DD;
#pragma unroll
        for (int h = 0; h < 2; h++) {
            const float* p = wrow + h * 32 + q * 8;
#pragma unroll
            for (int j = 0; j < 8; j++) bfr[t][h][j] = (short)f2bf(p[j]);
        }
        fb[t] = fcb[t * 16 + m];
        fu[t] = fus[t * 16 + m];
    }
    __syncthreads();

    float rb0 = 0.f, rb1 = 0.f;
    const int gw = blockIdx.x * 4 + wid;
    const int nw = gridDim.x * 4;
    for (int tile = gw; tile < N_NODES / 16; tile += nw) {
        const int rowbase = (tile * 16 + m) * DD + q * 8;  // A-frag: E[m][k=q*8+j]
        {
            const short8 a0 = *(const short8*)(e0bf + rowbase);
            const short8 a1 = *(const short8*)(e0bf + rowbase + 32);
            f32x4 c[4];
#pragma unroll
            for (int t = 0; t < 4; t++) {
                c[t] = f32x4{0.f, 0.f, 0.f, 0.f};
                c[t] = __builtin_amdgcn_mfma_f32_16x16x32_bf16(a0, bfr[t][0], c[t], 0, 0, 0);
                c[t] = __builtin_amdgcn_mfma_f32_16x16x32_bf16(a1, bfr[t][1], c[t], 0, 0, 0);
            }
#pragma unroll
            for (int t = 0; t < 4; t++)
#pragma unroll
                for (int j = 0; j < 4; j++)
                    rb0 += tanh_fast(c[t][j] + fb[t]) * fu[t];
        }
        {
            const short8 a0 = *(const short8*)(e1bf + rowbase);
            const short8 a1 = *(const short8*)(e1bf + rowbase + 32);
            f32x4 c[4];
#pragma unroll
            for (int t = 0; t < 4; t++) {
                c[t] = f32x4{0.f, 0.f, 0.f, 0.f};
                c[t] = __builtin_amdgcn_mfma_f32_16x16x32_bf16(a0, bfr[t][0], c[t], 0, 0, 0);
                c[t] = __builtin_amdgcn_mfma_f32_16x16x32_bf16(a1, bfr[t][1], c[t], 0, 0, 0);
            }
#pragma unroll
            for (int t = 0; t < 4; t++)
#pragma unroll
                for (int j = 0; j < 4; j++)
                    rb1 += tanh_fast(c[t][j] + fb[t]) * fu[t];
        }
    }
    const float b0 = wave_sum(rb0);
    const float b1 = wave_sum(rb1);
    if (lane == 0) { atomicAdd(&s_part[0], b0); atomicAdd(&s_part[1], b1); }
    __syncthreads();
    if (tid == 0) { atomicAdd(&accum[0], s_part[0]); atomicAdd(&accum[1], s_part[1]); }
}

// Kernel 4: final elementwise combine (bf16 e reads, f32 out).
__global__ __launch_bounds__(256) void k_out(
    const unsigned short* __restrict__ e0bf, const unsigned short* __restrict__ e1bf,
    const float* __restrict__ accum, const float* __restrict__ gate,
    float* __restrict__ out)
{
    const int i = blockIdx.x * 256 + threadIdx.x;   // float4 index, exact grid
    const float b0 = accum[0] * (1.f / N_NODES);
    const float b1 = accum[1] * (1.f / N_NODES);
    const float mx = fmaxf(b0, b1);
    const float eb0 = __expf(b0 - mx), eb1 = __expf(b1 - mx);
    const float gv  = 1.f / (1.f + __expf(-gate[0]));
    const float c0  = gv * eb0 / (eb0 + eb1);
    const float c1  = gv * eb1 / (eb0 + eb1);
    const float cg  = (1.f - gv) / accum[2];

    const float4 av = ((const float4*)(accum + 4))[i & 15];
    const ushort4 ua = ((const ushort4*)e0bf)[i];
    const ushort4 ub = ((const ushort4*)e1bf)[i];
    float4 o;
    o.x = c0 * bf2f(ua.x) + c1 * bf2f(ub.x) + cg * av.x;
    o.y = c0 * bf2f(ua.y) + c1 * bf2f(ub.y) + cg * av.y;
    o.z = c0 * bf2f(ua.z) + c1 * bf2f(ub.z) + cg * av.z;
    o.w = c0 * bf2f(ua.w) + c1 * bf2f(ub.w) + cg * av.w;
    ((float4*)out)[i] = o;
}

extern "C" void kernel_launch(void* const* d_in, const int* in_sizes, int n_in,
                              void* d_out, int out_size, void* d_ws, size_t ws_size,
                              hipStream_t stream) {
    (void)in_sizes; (void)n_in; (void)out_size; (void)ws_size;
    const float* h0   = (const float*)d_in[0];
    const float* h1   = (const float*)d_in[1];
    const float* h2   = (const float*)d_in[2];
    const int*   nei0 = (const int*)  d_in[3];
    const int*   nei1 = (const int*)  d_in[4];
    const float* aw0  = (const float*)d_in[5];
    const float* aw1  = (const float*)d_in[6];
    const float* fcw  = (const float*)d_in[7];
    const float* fcb  = (const float*)d_in[8];
    const float* fus  = (const float*)d_in[9];
    const float* gatt = (const float*)d_in[10];
    const float* gate = (const float*)d_in[11];
    float* out = (float*)d_out;

    // workspace layout (float offsets; bf16 areas cast to ushort*)
    float* ws    = (float*)d_ws;
    float* accum = ws;                               // [0]=b0 [1]=b1 [2]=sumexp [4..67]=wsum
    float* p0r0  = ws + 256;                         // N
    float* p0r1  = p0r0 + N_NODES;                   // N
    float* p1    = p0r1 + N_NODES;                   // M1
    float* p2    = p1 + M1_N;                        // M2
    unsigned short* h1bf = (unsigned short*)(p2 + M2_N);            // M1*64 bf16
    unsigned short* h2bf = h1bf + (size_t)M1_N * DD;                // M2*64 bf16
    unsigned short* e0bf = h2bf + (size_t)M2_N * DD;                // N*64 bf16
    unsigned short* e1bf = e0bf + (size_t)N_NODES * DD;             // N*64 bf16
    // total: 26.4 MB (< round-2's proven 31.5 MB footprint)

    hipMemsetAsync(accum, 0, 256 * sizeof(float), stream);
    k_proj<<<1024, 256, 0, stream>>>(h0, h1, h2, aw0, aw1, gatt, accum,
                                     p0r0, p0r1, p1, p2, h1bf, h2bf);
    k_attn<<<2048, 256, 0, stream>>>(h1bf, h2bf, nei0, nei1, p0r0, p0r1, p1, p2, e0bf, e1bf);
    k_beta<<<512, 256, 0, stream>>>(e0bf, e1bf, fcw, fcb, fus, accum);
    k_out<<<(N_NODES * DD / 4) / 256, 256, 0, stream>>>(e0bf, e1bf, accum, gate, out);
}